// Round 1
// baseline (51.181 us; speedup 1.0000x reference)
//
#include <hip/hip_runtime.h>

#define BS   2
#define NTOK 2048
#define NH   4
#define W    64
#define WIN  64
#define HALF 32

// One 64-lane wave per (b, h, d) output row. 4 waves per 256-thread block.
// grid = BS*NH*NTOK/4 = 4096 blocks.
__global__ __launch_bounds__(256) void l1attn_win64_kernel(
    const float* __restrict__ v,
    const float* __restrict__ q,
    const float* __restrict__ k,
    float* __restrict__ out)
{
    const int lane = threadIdx.x & 63;
    const int widx = threadIdx.x >> 6;
    const int gw   = blockIdx.x * 4 + widx;      // (b*NH + h)*NTOK + d

    const int d  = gw & (NTOK - 1);
    const int bh = gw >> 11;                      // log2(NTOK) = 11
    const int h  = bh & (NH - 1);
    const int b  = bh >> 2;                       // log2(NH) = 2

    const int qbase = ((b * NTOK + d) * NH + h) * W;

    // ---------------- phase 1: scores (lane j = window position j) ----------
    const int j    = lane;
    const int src  = (d + j - HALF + NTOK) & (NTOK - 1);
    const int kbase = ((b * NTOK + src) * NH + h) * W;

    const float4* q4 = (const float4*)(q + qbase);   // lane-uniform (broadcast)
    const float4* k4 = (const float4*)(k + kbase);   // per-lane row

    float acc = 0.f;
    #pragma unroll
    for (int i = 0; i < 16; ++i) {
        float4 qa = q4[i];
        float4 ka = k4[i];
        acc += fabsf(qa.x - ka.x) + fabsf(qa.y - ka.y)
             + fabsf(qa.z - ka.z) + fabsf(qa.w - ka.w);
    }
    float score = acc * -0.125f;                     // * (-1/sqrt(64))

    // ---------------- softmax across the 64 lanes ---------------------------
    float m = score;
    #pragma unroll
    for (int off = 32; off >= 1; off >>= 1)
        m = fmaxf(m, __shfl_xor(m, off));
    float e = __expf(score - m);
    float s = e;
    #pragma unroll
    for (int off = 32; off >= 1; off >>= 1)
        s += __shfl_xor(s, off);
    const float p = e / s;                           // lane j holds p_j

    // ---------------- phase 2: out = sum_j p_j * v[src_j, :] ----------------
    // remap: lane = r*16 + l ; this lane accumulates channels 4l..4l+3 over
    // rows jj = it*4 + r.
    const int l16 = lane & 15;
    const int r   = lane >> 4;

    float a0 = 0.f, a1 = 0.f, a2 = 0.f, a3 = 0.f;
    #pragma unroll
    for (int it = 0; it < 16; ++it) {
        const int jj   = it * 4 + r;
        const int srcj = (d + jj - HALF + NTOK) & (NTOK - 1);
        const float4* v4 = (const float4*)(v + ((b * NTOK + srcj) * NH + h) * W);
        const float4 vv = v4[l16];
        const float pj = __shfl(p, jj);              // broadcast from lane jj
        a0 += pj * vv.x; a1 += pj * vv.y; a2 += pj * vv.z; a3 += pj * vv.w;
    }
    // sum the 4 r-groups (lanes differing in bits 4 and 5)
    a0 += __shfl_xor(a0, 16); a1 += __shfl_xor(a1, 16);
    a2 += __shfl_xor(a2, 16); a3 += __shfl_xor(a3, 16);
    a0 += __shfl_xor(a0, 32); a1 += __shfl_xor(a1, 32);
    a2 += __shfl_xor(a2, 32); a3 += __shfl_xor(a3, 32);

    if (r == 0) {
        float4* o4 = (float4*)(out + qbase);
        o4[l16] = make_float4(a0, a1, a2, a3);
    }
}

extern "C" void kernel_launch(void* const* d_in, const int* in_sizes, int n_in,
                              void* d_out, int out_size, void* d_ws, size_t ws_size,
                              hipStream_t stream) {
    // setup_inputs order: v, q, k, coo, dst_mxlen, src_mxlen  (all f32 except coo/int)
    const float* v = (const float*)d_in[0];
    const float* q = (const float*)d_in[1];
    const float* k = (const float*)d_in[2];
    float* out = (float*)d_out;

    const int n_waves = BS * NH * NTOK;          // 16384
    const int blocks  = n_waves / 4;             // 4096
    hipLaunchKernelGGL(l1attn_win64_kernel, dim3(blocks), dim3(256), 0, stream,
                       v, q, k, out);
}

// Round 2
// 21.978 us; speedup vs baseline: 2.3288x; 2.3288x over previous
//
#include <hip/hip_runtime.h>

#define BS   2
#define NTOK 2048
#define NH   4
#define W    64
#define HALF 32

// DPP butterfly-add within a 16-lane row. CTRL: 0xB1=xor1(quad_perm[1,0,3,2]),
// 0x4E=xor2(quad_perm[2,3,0,1]), 0x141=row_half_mirror(xor7), 0x128=row_ror:8(xor8).
// {1,2,7,8} is a rank-4 basis of lane bits 0..3 -> butterfly over these four
// masks sums all 16 lanes of the row into every lane.
template<int CTRL>
__device__ __forceinline__ float fadd_dpp(float x) {
    int y = __builtin_amdgcn_mov_dpp(__float_as_int(x), CTRL, 0xF, 0xF, true);
    return x + __int_as_float(y);
}

// One 64-lane wave per (b, h, d). lane = r*16 + l: lane covers channels
// 4l..4l+3 of window rows jj = it*4 + r, it = 0..15. All global loads are
// 4x256B contiguous segments per wave-instruction (coalesced).
__global__ __launch_bounds__(256) void l1attn_win64_v2(
    const float* __restrict__ v,
    const float* __restrict__ q,
    const float* __restrict__ k,
    float* __restrict__ out)
{
    const int lane = threadIdx.x & 63;
    const int widx = threadIdx.x >> 6;

    // XCD-aware bijective swizzle: 4096 blocks, 8 XCDs, 512 blocks each.
    // XCD x handles one contiguous (b,h) slab of all 2048 d's -> L2-resident.
    int bid = blockIdx.x;
    bid = (bid & 7) * 512 + (bid >> 3);

    const int gw = bid * 4 + widx;               // (b*NH + h)*NTOK + d
    const int d  = gw & (NTOK - 1);
    const int bh = gw >> 11;                     // log2(NTOK)
    const int h  = bh & (NH - 1);
    const int b  = bh >> 2;
    const int bh_base = b * (NTOK * NH * W) + h * W;   // + tok*NH*W + chan

    const int l16 = lane & 15;
    const int r   = lane >> 4;

    // q chunk for this lane's channels (broadcast across r-groups)
    const float4 qv = *(const float4*)(q + bh_base + d * (NH * W) + l16 * 4);

    // ---------------- phase 1: partial |q-k| sums --------------------------
    float s16[16];
    #pragma unroll
    for (int it = 0; it < 16; ++it) {
        const int jj   = it * 4 + r;
        const int srcj = (d + jj - HALF) & (NTOK - 1);
        const float4 kv = *(const float4*)(k + bh_base + srcj * (NH * W) + l16 * 4);
        s16[it] = fabsf(qv.x - kv.x) + fabsf(qv.y - kv.y)
                + fabsf(qv.z - kv.z) + fabsf(qv.w - kv.w);
    }

    // 16-lane channel reduction, all on the VALU pipe via DPP
    #pragma unroll
    for (int it = 0; it < 16; ++it) {
        float t = s16[it];
        t = fadd_dpp<0xB1>(t);     // xor 1
        t = fadd_dpp<0x4E>(t);     // xor 2
        t = fadd_dpp<0x141>(t);    // xor 7 (row_half_mirror)
        t = fadd_dpp<0x128>(t);    // xor 8 (row_ror:8)
        s16[it] = t * -0.125f;     // * (-1/sqrt(64))
    }

    // ---------------- softmax over the 64 j's ------------------------------
    float m = s16[0];
    #pragma unroll
    for (int it = 1; it < 16; ++it) m = fmaxf(m, s16[it]);
    m = fmaxf(m, __shfl_xor(m, 16));
    m = fmaxf(m, __shfl_xor(m, 32));

    float ssum = 0.f;
    #pragma unroll
    for (int it = 0; it < 16; ++it) {
        s16[it] = __expf(s16[it] - m);
        ssum += s16[it];
    }
    ssum += __shfl_xor(ssum, 16);
    ssum += __shfl_xor(ssum, 32);
    const float inv = 1.0f / ssum;

    // ---------------- phase 2: out += p_j * v[src_j, :] --------------------
    // p[it] for row jj=it*4+r lives in this lane already - no broadcasts.
    float a0 = 0.f, a1 = 0.f, a2 = 0.f, a3 = 0.f;
    #pragma unroll
    for (int it = 0; it < 16; ++it) {
        const int jj   = it * 4 + r;
        const int srcj = (d + jj - HALF) & (NTOK - 1);
        const float4 vv = *(const float4*)(v + bh_base + srcj * (NH * W) + l16 * 4);
        const float pj = s16[it] * inv;
        a0 += pj * vv.x; a1 += pj * vv.y; a2 += pj * vv.z; a3 += pj * vv.w;
    }
    // sum the 4 r-groups
    a0 += __shfl_xor(a0, 16); a1 += __shfl_xor(a1, 16);
    a2 += __shfl_xor(a2, 16); a3 += __shfl_xor(a3, 16);
    a0 += __shfl_xor(a0, 32); a1 += __shfl_xor(a1, 32);
    a2 += __shfl_xor(a2, 32); a3 += __shfl_xor(a3, 32);

    if (r == 0) {
        *(float4*)(out + bh_base + d * (NH * W) + l16 * 4)
            = make_float4(a0, a1, a2, a3);
    }
}

extern "C" void kernel_launch(void* const* d_in, const int* in_sizes, int n_in,
                              void* d_out, int out_size, void* d_ws, size_t ws_size,
                              hipStream_t stream) {
    // setup_inputs order: v, q, k, coo, dst_mxlen, src_mxlen
    const float* v = (const float*)d_in[0];
    const float* q = (const float*)d_in[1];
    const float* k = (const float*)d_in[2];
    float* out = (float*)d_out;

    const int blocks = (BS * NH * NTOK) / 4;     // 4096
    hipLaunchKernelGGL(l1attn_win64_v2, dim3(blocks), dim3(256), 0, stream,
                       v, q, k, out);
}